// Round 16
// baseline (1602.494 us; speedup 1.0000x reference)
//
#include <hip/hip_runtime.h>
#include <hip/hip_bf16.h>

#define DEVINL __device__ __forceinline__

constexpr int Bsz = 4096, INF = 1024, H1 = 2048, H2 = 2048, OUTD = 512, NE = 8, G = 256;

typedef __attribute__((ext_vector_type(8))) short bf16x8;
typedef __attribute__((ext_vector_type(4))) float f32x4;
typedef unsigned short u16;

DEVINL u16 f2bf(float f) {  // RNE f32 -> bf16 bits
  unsigned int u = __float_as_uint(f);
  u = (u + 0x7FFFu + ((u >> 16) & 1u)) >> 16;
  return (u16)u;
}
DEVINL float bf2f(u16 h) { return __uint_as_float((unsigned int)h << 16); }

DEVINL void gload16(const void* g, void* l) {
  __builtin_amdgcn_global_load_lds(
      (const __attribute__((address_space(1))) void*)g,
      (__attribute__((address_space(3))) void*)l, 16, 0, 0);
}

DEVINL float waveAllSum(float v) {
#pragma unroll
  for (int m = 32; m > 0; m >>= 1) v += __shfl_xor(v, m, 64);
  return v;
}

// ---------------- pack W[e][K][N] f32 -> Wt hi/lo bf16 [e][N][K] ----------------
__global__ __launch_bounds__(256) void pack_wt(const float* __restrict__ W,
                                               u16* __restrict__ Th,
                                               u16* __restrict__ Tl,
                                               int K, int N) {
  __shared__ float t[32][33];
  const int e = blockIdx.z;
  W += (size_t)e * K * N;
  Th += (size_t)e * N * K;
  Tl += (size_t)e * N * K;
  const int n0 = blockIdx.x * 32, k0 = blockIdx.y * 32;
  const int r = threadIdx.x >> 3, c = (threadIdx.x & 7) * 4;
  float4 v = *(const float4*)&W[(size_t)(k0 + r) * N + n0 + c];
  t[r][c + 0] = v.x; t[r][c + 1] = v.y; t[r][c + 2] = v.z; t[r][c + 3] = v.w;
  __syncthreads();
  float o0 = t[c + 0][r], o1 = t[c + 1][r], o2 = t[c + 2][r], o3 = t[c + 3][r];
  short4 h, l;
  h.x = f2bf(o0); l.x = f2bf(o0 - bf2f(h.x));
  h.y = f2bf(o1); l.y = f2bf(o1 - bf2f(h.y));
  h.z = f2bf(o2); l.z = f2bf(o2 - bf2f(h.z));
  h.w = f2bf(o3); l.w = f2bf(o3 - bf2f(h.w));
  *(short4*)&Th[(size_t)(n0 + r) * K + k0 + c] = h;
  *(short4*)&Tl[(size_t)(n0 + r) * K + k0 + c] = l;
}

// ============ L1/L2 GEMM: 256x256 tile, 16x16x32 bf16x3, 1 barrier/K-tile ======
// B = 3-slot ring (t%3): stageB(t+2) never aliases the slot being read, so the
// mid-tile barrier is gone. A = 2-slot (t&1), staged at distance 1 (issued at
// tile top, waited one full tile later). Counted vmcnt(4) at end of tile leaves
// only B(t+2) in flight => A(t+1),B(t+1) landed. LDS: Ahi 2x16K @0, Alo 2x16K
// @32768, Bhi 3x16K @65536, Blo 3x16K @114688 = 163840 B.
__global__ __launch_bounds__(512, 2) void gemm_2bar(
    const u16* __restrict__ Ahi, const u16* __restrict__ Alo,
    const u16* __restrict__ Bhi, const u16* __restrict__ Blo,
    const float* __restrict__ bias,
    u16* __restrict__ Chi, u16* __restrict__ Clo,
    int M, int N, int K, size_t strideAe) {
  const int e = blockIdx.x;  // XCD = linear%8 = e
  Ahi += (size_t)e * strideAe;
  Alo += (size_t)e * strideAe;
  Bhi += (size_t)e * (size_t)N * K;
  Blo += (size_t)e * (size_t)N * K;
  bias += (size_t)e * N;
  Chi += (size_t)e * (size_t)M * N;
  Clo += (size_t)e * (size_t)M * N;

  const int bm = blockIdx.y * 256, bn = blockIdx.z * 256;
  __shared__ __align__(16) char ldsb[163840];
  const int lane = threadIdx.x & 63, wid = threadIdx.x >> 6;
  const int wm = wid >> 2, wn = wid & 3;
  const int l15 = lane & 15, l4 = lane >> 4;
  const int bhalf = wn >> 1, jn = wn & 1;

  f32x4 acc[8][4];
#pragma unroll
  for (int i = 0; i < 8; ++i)
#pragma unroll
    for (int j = 0; j < 4; ++j) acc[i][j] = (f32x4){0.f, 0.f, 0.f, 0.f};

  const int nt = K / 32;

  // A: 2 gloads/wave per op (Ahi or Alo); slot = T&1
  auto stageA = [&](const u16* src, int T, int ldsOp) {
    const int slot = T & 1;
#pragma unroll
    for (int q = 0; q < 2; ++q) {
      const int g = wid * 2 + q;  // 0..15 = frag (16 rows each)
      gload16(src + (size_t)(bm + g * 16 + l15) * K + T * 32 + l4 * 8,
              ldsb + ldsOp + slot * 16384 + g * 1024);
    }
  };
  // B: both hi+lo in one call, 4 gloads/wave; slot passed in (t%3)
  auto stageB = [&](int T, int slot) {
#pragma unroll
    for (int q = 0; q < 4; ++q) {
      const int g = wid * 4 + q;  // <16: Bhi frag g, >=16: Blo frag g-16
      const u16* src = (g < 16) ? Bhi : Blo;
      const int f = g & 15;
      gload16(src + (size_t)(bn + f * 16 + l15) * K + T * 32 + l4 * 8,
              ldsb + ((g < 16) ? 65536 : 114688) + slot * 16384 + f * 1024);
    }
  };

  bf16x8 ah[4], al[4], bh[4], bl[4];
  auto readA = [&](int slot, int ih) {
#pragma unroll
    for (int i = 0; i < 4; ++i) {
      const int off = slot * 16384 + wm * 8192 + (ih * 4 + i) * 1024 + lane * 16;
      ah[i] = *(const bf16x8*)(ldsb + off);
      al[i] = *(const bf16x8*)(ldsb + 32768 + off);
    }
  };
  auto readBall = [&](int sB) {
#pragma unroll
    for (int j = 0; j < 4; ++j) {
      const int off = sB * 16384 + bhalf * 8192 + (jn * 4 + j) * 1024 + lane * 16;
      bh[j] = *(const bf16x8*)(ldsb + 65536 + off);
      bl[j] = *(const bf16x8*)(ldsb + 114688 + off);
    }
  };

#define QUAD48(IH)                                                             \
  _Pragma("unroll") for (int i = 0; i < 4; ++i) {                              \
    _Pragma("unroll") for (int j = 0; j < 4; ++j) {                            \
      f32x4 a = acc[(IH)*4 + i][j];                                            \
      a = __builtin_amdgcn_mfma_f32_16x16x32_bf16(bh[j], ah[i], a, 0, 0, 0);   \
      a = __builtin_amdgcn_mfma_f32_16x16x32_bf16(bl[j], ah[i], a, 0, 0, 0);   \
      a = __builtin_amdgcn_mfma_f32_16x16x32_bf16(bh[j], al[i], a, 0, 0, 0);   \
      acc[(IH)*4 + i][j] = a;                                                  \
    }                                                                          \
  }

  // prologue: B(0)[4], A(0)[4], B(1)[4]; vmcnt(4) lands B(0)+A(0), B(1) stays
  stageB(0, 0);
  stageA(Ahi, 0, 0); stageA(Alo, 0, 32768);
  stageB(1, 1);
  asm volatile("s_waitcnt vmcnt(4)" ::: "memory");
  __builtin_amdgcn_sched_barrier(0);
  __builtin_amdgcn_s_barrier();
  __builtin_amdgcn_sched_barrier(0);

  int bS = 0, bS2 = 2;  // t%3, (t+2)%3
  for (int t = 0; t < nt - 2; ++t) {
    const int sA = t & 1;
    readA(sA, 0);
    readBall(bS);
    __builtin_amdgcn_sched_barrier(0);  // reads issued before staging
    stageA(Ahi, t + 1, 0); stageA(Alo, t + 1, 32768);
    stageB(t + 2, bS2);
    QUAD48(0);
    readA(sA, 1);
    QUAD48(1);
    // leave only B(t+2)[4] in flight; forces B(t+1)+A(t+1) landed
    asm volatile("s_waitcnt vmcnt(4)" ::: "memory");
    __builtin_amdgcn_sched_barrier(0);
    __builtin_amdgcn_s_barrier();
    __builtin_amdgcn_sched_barrier(0);
    bS = (bS == 2) ? 0 : bS + 1;
    bS2 = (bS2 == 2) ? 0 : bS2 + 1;
  }
  // tail t = nt-2: stage A(nt-1) only; drain
  {
    const int sA = (nt - 2) & 1;
    readA(sA, 0);
    readBall(bS);
    __builtin_amdgcn_sched_barrier(0);
    stageA(Ahi, nt - 1, 0); stageA(Alo, nt - 1, 32768);
    QUAD48(0);
    readA(sA, 1);
    QUAD48(1);
    asm volatile("s_waitcnt vmcnt(0)" ::: "memory");
    __builtin_amdgcn_sched_barrier(0);
    __builtin_amdgcn_s_barrier();
    __builtin_amdgcn_sched_barrier(0);
    bS = (bS == 2) ? 0 : bS + 1;
  }
  // tail t = nt-1: reads + MFMA only
  {
    const int sA = (nt - 1) & 1;
    readA(sA, 0);
    readBall(bS);
    QUAD48(0);
    readA(sA, 1);
    QUAD48(1);
  }
#undef QUAD48

  // epilogue: lane holds C[row=bm+wm*128+i*16+l15][col=bn+wn*64+j*16+l4*4+q]
#pragma unroll
  for (int i = 0; i < 8; ++i) {
    const int grow = bm + wm * 128 + i * 16 + l15;
#pragma unroll
    for (int j = 0; j < 4; ++j) {
      const int gcol = bn + wn * 64 + j * 16 + l4 * 4;
      const float4 bb = *(const float4*)&bias[gcol];
      float v0 = fmaxf(acc[i][j][0] + bb.x, 0.f);
      float v1 = fmaxf(acc[i][j][1] + bb.y, 0.f);
      float v2 = fmaxf(acc[i][j][2] + bb.z, 0.f);
      float v3 = fmaxf(acc[i][j][3] + bb.w, 0.f);
      short4 h, l;
      h.x = f2bf(v0); l.x = f2bf(v0 - bf2f(h.x));
      h.y = f2bf(v1); l.y = f2bf(v1 - bf2f(h.y));
      h.z = f2bf(v2); l.z = f2bf(v2 - bf2f(h.z));
      h.w = f2bf(v3); l.w = f2bf(v3 - bf2f(h.w));
      *(short4*)&Chi[(size_t)grow * N + gcol] = h;
      *(short4*)&Clo[(size_t)grow * N + gcol] = l;
    }
  }
}

// ============ L3 GEMM: 128x256 tile, 16x16x32 bf16x3, 1 barrier/K-tile =========
// Same single-barrier structure: A 2-slot (8KB/slot/op) distance-1, B 3-slot
// ring (16KB/slot/op) distance-2. LDS: Ahi 2x8K @0, Alo 2x8K @16384,
// Bhi 3x16K @32768, Blo 3x16K @81920 = 131072 B. vmcnt(4). f32 out, no relu.
__global__ __launch_bounds__(512, 2) void gemm_l3(
    const u16* __restrict__ Ahi, const u16* __restrict__ Alo,
    const u16* __restrict__ Bhi, const u16* __restrict__ Blo,
    const float* __restrict__ bias, float* __restrict__ Cf,
    int M, int N, int K, size_t strideAe) {
  const int e = blockIdx.x;
  Ahi += (size_t)e * strideAe;
  Alo += (size_t)e * strideAe;
  Bhi += (size_t)e * (size_t)N * K;
  Blo += (size_t)e * (size_t)N * K;
  bias += (size_t)e * N;
  Cf += (size_t)e * (size_t)M * N;

  const int bm = blockIdx.y * 128, bn = blockIdx.z * 256;
  __shared__ __align__(16) char ldsb[131072];
  const int lane = threadIdx.x & 63, wid = threadIdx.x >> 6;
  const int wm = wid >> 2, wn = wid & 3;
  const int l15 = lane & 15, l4 = lane >> 4;
  const int bhalf = wn >> 1, jn = wn & 1;

  f32x4 acc[4][4];
#pragma unroll
  for (int i = 0; i < 4; ++i)
#pragma unroll
    for (int j = 0; j < 4; ++j) acc[i][j] = (f32x4){0.f, 0.f, 0.f, 0.f};

  const int nt = K / 32;

  // A: both hi+lo in one call, 2 gloads/wave; slot = T&1
  auto stageA3 = [&](int T) {
    const int slot = T & 1;
#pragma unroll
    for (int q = 0; q < 2; ++q) {
      const int g = wid * 2 + q;  // <8: Ahi frag g, >=8: Alo frag g-8
      const u16* src = (g < 8) ? Ahi : Alo;
      const int f = g & 7;
      gload16(src + (size_t)(bm + f * 16 + l15) * K + T * 32 + l4 * 8,
              ldsb + ((g < 8) ? 0 : 16384) + slot * 8192 + f * 1024);
    }
  };
  // B: both hi+lo, 4 gloads/wave; slot passed in (t%3)
  auto stageB = [&](int T, int slot) {
#pragma unroll
    for (int q = 0; q < 4; ++q) {
      const int g = wid * 4 + q;  // <16: Bhi frag g, >=16: Blo frag g-16
      const u16* src = (g < 16) ? Bhi : Blo;
      const int f = g & 15;
      gload16(src + (size_t)(bn + f * 16 + l15) * K + T * 32 + l4 * 8,
              ldsb + ((g < 16) ? 32768 : 81920) + slot * 16384 + f * 1024);
    }
  };

  bf16x8 ah[2], al[2], bh[4], bl[4];
  auto readA = [&](int slot, int ih) {
#pragma unroll
    for (int i = 0; i < 2; ++i) {
      const int off = slot * 8192 + (wm * 4 + ih * 2 + i) * 1024 + lane * 16;
      ah[i] = *(const bf16x8*)(ldsb + off);
      al[i] = *(const bf16x8*)(ldsb + 16384 + off);
    }
  };
  auto readBall = [&](int sB) {
#pragma unroll
    for (int j = 0; j < 4; ++j) {
      const int off = sB * 16384 + bhalf * 8192 + (jn * 4 + j) * 1024 + lane * 16;
      bh[j] = *(const bf16x8*)(ldsb + 32768 + off);
      bl[j] = *(const bf16x8*)(ldsb + 81920 + off);
    }
  };

#define QUAD24(IH)                                                             \
  _Pragma("unroll") for (int i = 0; i < 2; ++i) {                              \
    _Pragma("unroll") for (int j = 0; j < 4; ++j) {                            \
      f32x4 a = acc[(IH)*2 + i][j];                                            \
      a = __builtin_amdgcn_mfma_f32_16x16x32_bf16(bh[j], ah[i], a, 0, 0, 0);   \
      a = __builtin_amdgcn_mfma_f32_16x16x32_bf16(bl[j], ah[i], a, 0, 0, 0);   \
      a = __builtin_amdgcn_mfma_f32_16x16x32_bf16(bh[j], al[i], a, 0, 0, 0);   \
      acc[(IH)*2 + i][j] = a;                                                  \
    }                                                                          \
  }

  // prologue: B(0)[4], A(0)[2], B(1)[4]; vmcnt(4) lands B(0)+A(0)
  stageB(0, 0);
  stageA3(0);
  stageB(1, 1);
  asm volatile("s_waitcnt vmcnt(4)" ::: "memory");
  __builtin_amdgcn_sched_barrier(0);
  __builtin_amdgcn_s_barrier();
  __builtin_amdgcn_sched_barrier(0);

  int bS = 0, bS2 = 2;  // t%3, (t+2)%3
  for (int t = 0; t < nt - 2; ++t) {
    const int sA = t & 1;
    readA(sA, 0);
    readBall(bS);
    __builtin_amdgcn_sched_barrier(0);
    stageA3(t + 1);
    stageB(t + 2, bS2);
    QUAD24(0);
    readA(sA, 1);
    QUAD24(1);
    // leave only B(t+2)[4] in flight; forces B(t+1)[4]+A(t+1)[2] landed
    asm volatile("s_waitcnt vmcnt(4)" ::: "memory");
    __builtin_amdgcn_sched_barrier(0);
    __builtin_amdgcn_s_barrier();
    __builtin_amdgcn_sched_barrier(0);
    bS = (bS == 2) ? 0 : bS + 1;
    bS2 = (bS2 == 2) ? 0 : bS2 + 1;
  }
  // tail t = nt-2: stage A(nt-1) only; drain
  {
    const int sA = (nt - 2) & 1;
    readA(sA, 0);
    readBall(bS);
    __builtin_amdgcn_sched_barrier(0);
    stageA3(nt - 1);
    QUAD24(0);
    readA(sA, 1);
    QUAD24(1);
    asm volatile("s_waitcnt vmcnt(0)" ::: "memory");
    __builtin_amdgcn_sched_barrier(0);
    __builtin_amdgcn_s_barrier();
    __builtin_amdgcn_sched_barrier(0);
    bS = (bS == 2) ? 0 : bS + 1;
  }
  // tail t = nt-1
  {
    const int sA = (nt - 1) & 1;
    readA(sA, 0);
    readBall(bS);
    QUAD24(0);
    readA(sA, 1);
    QUAD24(1);
  }
#undef QUAD24

  // epilogue: lane holds C[row=bm+wm*64+i*16+l15][col=bn+wn*64+j*16+l4*4+q]
#pragma unroll
  for (int i = 0; i < 4; ++i) {
    const int grow = bm + wm * 64 + i * 16 + l15;
#pragma unroll
    for (int j = 0; j < 4; ++j) {
      const int gcol = bn + wn * 64 + j * 16 + l4 * 4;
      const float4 bb = *(const float4*)&bias[gcol];
      *(float4*)&Cf[(size_t)grow * N + gcol] =
          make_float4(acc[i][j][0] + bb.x, acc[i][j][1] + bb.y,
                      acc[i][j][2] + bb.z, acc[i][j][3] + bb.w);
    }
  }
}

// ---------------- gate layer 1 (+ fused x -> hi/lo pack) ----------------
__global__ __launch_bounds__(256) void gate1_kernel(
    const float* __restrict__ x, const float* __restrict__ Wg1,
    const float* __restrict__ bg1, float* __restrict__ g,
    u16* __restrict__ xhi, u16* __restrict__ xlo) {
  __shared__ float xs[8 * 1024];
  const int b0 = blockIdx.x * 8;
  const size_t base = (size_t)b0 * INF;
  const float* xp = x + base;
  for (int idx = threadIdx.x * 4; idx < 8 * 1024; idx += 1024) {
    float4 v = *(const float4*)&xp[idx];
    *(float4*)&xs[idx] = v;
    short4 h, l;
    h.x = f2bf(v.x); l.x = f2bf(v.x - bf2f(h.x));
    h.y = f2bf(v.y); l.y = f2bf(v.y - bf2f(h.y));
    h.z = f2bf(v.z); l.z = f2bf(v.z - bf2f(h.z));
    h.w = f2bf(v.w); l.w = f2bf(v.w - bf2f(h.w));
    *(short4*)&xhi[base + idx] = h;
    *(short4*)&xlo[base + idx] = l;
  }
  __syncthreads();
  const int t = threadIdx.x;
  float acc[8] = {0, 0, 0, 0, 0, 0, 0, 0};
  for (int i = 0; i < INF; ++i) {
    float w = Wg1[(size_t)i * G + t];
#pragma unroll
    for (int r = 0; r < 8; ++r) acc[r] = fmaf(xs[r * 1024 + i], w, acc[r]);
  }
  const float bb = bg1[t];
#pragma unroll
  for (int r = 0; r < 8; ++r)
    g[(size_t)(b0 + r) * G + t] = fmaxf(acc[r] + bb, 0.0f);
}

// ---------------- gate layer 2 + softmax ----------------
__global__ __launch_bounds__(64) void gate2_kernel(
    const float* __restrict__ g, const float* __restrict__ Wg2,
    const float* __restrict__ bg2, float* __restrict__ gw) {
  const int b = blockIdx.x, lane = threadIdx.x;
  float4 gv = *(const float4*)(g + (size_t)b * G + lane * 4);
  float p[8];
#pragma unroll
  for (int e = 0; e < 8; ++e) {
    int j = lane * 4;
    float s = gv.x * Wg2[(j + 0) * 8 + e] + gv.y * Wg2[(j + 1) * 8 + e] +
              gv.z * Wg2[(j + 2) * 8 + e] + gv.w * Wg2[(j + 3) * 8 + e];
    p[e] = waveAllSum(s);
  }
  if (lane == 0) {
    float l[8];
    float mx = -1e30f;
#pragma unroll
    for (int e = 0; e < 8; ++e) {
      l[e] = p[e] + bg2[e];
      mx = fmaxf(mx, l[e]);
    }
    float sum = 0.0f;
#pragma unroll
    for (int e = 0; e < 8; ++e) {
      l[e] = expf(l[e] - mx);
      sum += l[e];
    }
    float inv = 1.0f / sum;
#pragma unroll
    for (int e = 0; e < 8; ++e) gw[(size_t)b * 8 + e] = l[e] * inv;
  }
}

// ---------------- Gram-Schmidt + combine + out-proj ----------------
__global__ __launch_bounds__(256) void gs_kernel(
    const float* __restrict__ eo, const float* __restrict__ gw,
    const float* __restrict__ Wo, const float* __restrict__ bo,
    float* __restrict__ out, int CB) {
  const int lane = threadIdx.x & 63;
  const int b = blockIdx.x * 4 + (threadIdx.x >> 6);
  const size_t ES = (size_t)CB * OUTD;
  const float* base = eo + (size_t)b * OUTD + lane * 8;
  float vs[8][8];
  float denom[8];
#pragma unroll
  for (int i = 0; i < 8; ++i) {
    float cur[8];
    float4 u0 = *(const float4*)(base + (size_t)i * ES);
    float4 u1 = *(const float4*)(base + (size_t)i * ES + 4);
    cur[0] = u0.x; cur[1] = u0.y; cur[2] = u0.z; cur[3] = u0.w;
    cur[4] = u1.x; cur[5] = u1.y; cur[6] = u1.z; cur[7] = u1.w;
#pragma unroll
    for (int j = 0; j < i; ++j) {
      float dp = 0.0f;
#pragma unroll
      for (int d = 0; d < 8; ++d) dp = fmaf(cur[d], vs[j][d], dp);
      dp = waveAllSum(dp);
      float coeff = dp / (denom[j] + 1e-6f);
#pragma unroll
      for (int d = 0; d < 8; ++d) cur[d] = fmaf(-coeff, vs[j][d], cur[d]);
    }
    float nn = 0.0f;
#pragma unroll
    for (int d = 0; d < 8; ++d) nn = fmaf(cur[d], cur[d], nn);
    nn = waveAllSum(nn);
    float inv = 1.0f / fmaxf(sqrtf(nn), 1e-6f);
#pragma unroll
    for (int d = 0; d < 8; ++d) vs[i][d] = cur[d] * inv;
    float dd = 0.0f;
#pragma unroll
    for (int d = 0; d < 8; ++d) dd = fmaf(vs[i][d], vs[i][d], dd);
    denom[i] = waveAllSum(dd);
  }
  float gwv[8];
#pragma unroll
  for (int e = 0; e < 8; ++e) gwv[e] = gw[(size_t)b * 8 + e];
  float part = 0.0f;
#pragma unroll
  for (int d = 0; d < 8; ++d) {
    float c = 0.0f;
#pragma unroll
    for (int e = 0; e < 8; ++e) c = fmaf(vs[e][d], gwv[e], c);
    part = fmaf(c, Wo[lane * 8 + d], part);
  }
  part = waveAllSum(part);
  if (lane == 0) out[b] = part + bo[0];
}

extern "C" void kernel_launch(void* const* d_in, const int* in_sizes, int n_in,
                              void* d_out, int out_size, void* d_ws, size_t ws_size,
                              hipStream_t stream) {
  const float* x   = (const float*)d_in[0];
  const float* W1  = (const float*)d_in[1];
  const float* b1  = (const float*)d_in[2];
  const float* W2  = (const float*)d_in[3];
  const float* b2  = (const float*)d_in[4];
  const float* W3  = (const float*)d_in[5];
  const float* b3  = (const float*)d_in[6];
  const float* Wg1 = (const float*)d_in[7];
  const float* bg1 = (const float*)d_in[8];
  const float* Wg2 = (const float*)d_in[9];
  const float* bg2 = (const float*)d_in[10];
  const float* Wo  = (const float*)d_in[11];
  const float* bo  = (const float*)d_in[12];
  float* out = (float*)d_out;

  char* p = (char*)d_ws;
  float* gw = (float*)p;          p += (size_t)(128u << 10);
  float* g  = (float*)p;          p += (size_t)(4u << 20);
  u16* xhi = (u16*)p;             p += (size_t)Bsz * INF * 2;
  u16* xlo = (u16*)p;             p += (size_t)Bsz * INF * 2;
  u16* w1h = (u16*)p;             p += (size_t)NE * H1 * INF * 2;
  u16* w1l = (u16*)p;             p += (size_t)NE * H1 * INF * 2;
  u16* w2h = (u16*)p;             p += (size_t)NE * H2 * H1 * 2;
  u16* w2l = (u16*)p;             p += (size_t)NE * H2 * H1 * 2;
  u16* w3h = (u16*)p;             p += (size_t)NE * OUTD * H2 * 2;
  u16* w3l = (u16*)p;             p += (size_t)NE * OUTD * H2 * 2;
  const size_t fixedBytes = (size_t)(p - (char*)d_ws);

  // chunk region: h1 hi/lo + h2 hi/lo = CB*128KB; CB multiple of 256
  int CB = 4096;
  while (CB > 256 && fixedBytes + (size_t)CB * (size_t)(128u << 10) > ws_size) CB >>= 1;
  u16* h1h = (u16*)p;
  u16* h1l = h1h + (size_t)NE * CB * H1;
  u16* h2h = h1l + (size_t)NE * CB * H1;
  u16* h2l = h2h + (size_t)NE * CB * H2;
  float* eo = (float*)h1h;  // layer-3 f32 out reuses h1 region (dead by then)

  hipMemsetAsync(d_out, 0, (size_t)out_size * sizeof(float), stream);

  // gate1 also packs x -> xhi/xlo (x rows pass through its registers anyway)
  gate1_kernel<<<Bsz / 8, 256, 0, stream>>>(x, Wg1, bg1, g, xhi, xlo);
  gate2_kernel<<<Bsz, 64, 0, stream>>>(g, Wg2, bg2, gw);

  pack_wt<<<dim3(H1 / 32, INF / 32, NE), 256, 0, stream>>>(W1, w1h, w1l, INF, H1);
  pack_wt<<<dim3(H2 / 32, H1 / 32, NE), 256, 0, stream>>>(W2, w2h, w2l, H1, H2);
  pack_wt<<<dim3(OUTD / 32, H2 / 32, NE), 256, 0, stream>>>(W3, w3h, w3l, H2, OUTD);

  for (int c0 = 0; c0 < Bsz; c0 += CB) {
    gemm_2bar<<<dim3(NE, CB / 256, H1 / 256), 512, 0, stream>>>(
        xhi + (size_t)c0 * INF, xlo + (size_t)c0 * INF, w1h, w1l, b1,
        h1h, h1l, CB, H1, INF, (size_t)0);
    gemm_2bar<<<dim3(NE, CB / 256, H2 / 256), 512, 0, stream>>>(
        h1h, h1l, w2h, w2l, b2, h2h, h2l, CB, H2, H1, (size_t)CB * H1);
    gemm_l3<<<dim3(NE, CB / 128, OUTD / 256), 512, 0, stream>>>(
        h2h, h2l, w3h, w3l, b3, eo, CB, OUTD, H2, (size_t)CB * H2);
    gs_kernel<<<CB / 4, 256, 0, stream>>>(eo, gw + (size_t)c0 * NE, Wo, bo,
                                          out + c0, CB);
  }
}

// Round 17
// 1513.245 us; speedup vs baseline: 1.0590x; 1.0590x over previous
//
#include <hip/hip_runtime.h>
#include <hip/hip_bf16.h>

#define DEVINL __device__ __forceinline__

constexpr int Bsz = 4096, INF = 1024, H1 = 2048, H2 = 2048, OUTD = 512, NE = 8, G = 256;

typedef __attribute__((ext_vector_type(8))) short bf16x8;
typedef __attribute__((ext_vector_type(4))) float f32x4;
typedef unsigned short u16;

DEVINL u16 f2bf(float f) {  // RNE f32 -> bf16 bits
  unsigned int u = __float_as_uint(f);
  u = (u + 0x7FFFu + ((u >> 16) & 1u)) >> 16;
  return (u16)u;
}
DEVINL float bf2f(u16 h) { return __uint_as_float((unsigned int)h << 16); }

DEVINL void gload16(const void* g, void* l) {
  __builtin_amdgcn_global_load_lds(
      (const __attribute__((address_space(1))) void*)g,
      (__attribute__((address_space(3))) void*)l, 16, 0, 0);
}

DEVINL float waveAllSum(float v) {
#pragma unroll
  for (int m = 32; m > 0; m >>= 1) v += __shfl_xor(v, m, 64);
  return v;
}

// ---------------- pack W[e][K][N] f32 -> Wt hi/lo bf16 [e][N][K] ----------------
__global__ __launch_bounds__(256) void pack_wt(const float* __restrict__ W,
                                               u16* __restrict__ Th,
                                               u16* __restrict__ Tl,
                                               int K, int N) {
  __shared__ float t[32][33];
  const int e = blockIdx.z;
  W += (size_t)e * K * N;
  Th += (size_t)e * N * K;
  Tl += (size_t)e * N * K;
  const int n0 = blockIdx.x * 32, k0 = blockIdx.y * 32;
  const int r = threadIdx.x >> 3, c = (threadIdx.x & 7) * 4;
  float4 v = *(const float4*)&W[(size_t)(k0 + r) * N + n0 + c];
  t[r][c + 0] = v.x; t[r][c + 1] = v.y; t[r][c + 2] = v.z; t[r][c + 3] = v.w;
  __syncthreads();
  float o0 = t[c + 0][r], o1 = t[c + 1][r], o2 = t[c + 2][r], o3 = t[c + 3][r];
  short4 h, l;
  h.x = f2bf(o0); l.x = f2bf(o0 - bf2f(h.x));
  h.y = f2bf(o1); l.y = f2bf(o1 - bf2f(h.y));
  h.z = f2bf(o2); l.z = f2bf(o2 - bf2f(h.z));
  h.w = f2bf(o3); l.w = f2bf(o3 - bf2f(h.w));
  *(short4*)&Th[(size_t)(n0 + r) * K + k0 + c] = h;
  *(short4*)&Tl[(size_t)(n0 + r) * K + k0 + c] = l;
}

// ============ L1/L2 GEMM: 256x256 tile, 16x16x32 bf16x3, 160KB LDS =============
// CHAMPION (R14, 1532us): A 3-slot ring (depth-2), B 2-slot, 2 barriers/K-tile,
// counted vmcnt(8), no lgkm drains.
__global__ __launch_bounds__(512, 2) void gemm_2bar(
    const u16* __restrict__ Ahi, const u16* __restrict__ Alo,
    const u16* __restrict__ Bhi, const u16* __restrict__ Blo,
    const float* __restrict__ bias,
    u16* __restrict__ Chi, u16* __restrict__ Clo,
    int M, int N, int K, size_t strideAe) {
  const int e = blockIdx.x;  // XCD = linear%8 = e
  Ahi += (size_t)e * strideAe;
  Alo += (size_t)e * strideAe;
  Bhi += (size_t)e * (size_t)N * K;
  Blo += (size_t)e * (size_t)N * K;
  bias += (size_t)e * N;
  Chi += (size_t)e * (size_t)M * N;
  Clo += (size_t)e * (size_t)M * N;

  const int bm = blockIdx.y * 256, bn = blockIdx.z * 256;
  __shared__ __align__(16) char ldsb[163840];
  const int lane = threadIdx.x & 63, wid = threadIdx.x >> 6;
  const int wm = wid >> 2, wn = wid & 3;
  const int l15 = lane & 15, l4 = lane >> 4;
  const int bhalf = wn >> 1, jn = wn & 1;

  f32x4 acc[8][4];
#pragma unroll
  for (int i = 0; i < 8; ++i)
#pragma unroll
    for (int j = 0; j < 4; ++j) acc[i][j] = (f32x4){0.f, 0.f, 0.f, 0.f};

  const int nt = K / 32;

  auto stageA = [&](const u16* src, int T, int slot, int ldsOp) {
#pragma unroll
    for (int q = 0; q < 2; ++q) {
      const int g = wid * 2 + q;  // 0..15 = half*8 + frag
      gload16(src + (size_t)(bm + g * 16 + l15) * K + T * 32 + l4 * 8,
              ldsb + ldsOp + slot * 16384 + g * 1024);
    }
  };
  auto stageB = [&](int T, int h) {
    const int s = T & 1;
#pragma unroll
    for (int q = 0; q < 2; ++q) {
      const int g = wid * 2 + q;  // <8: Bhi frag g, >=8: Blo frag g-8
      const u16* src = (g < 8) ? Bhi : Blo;
      const int f = g & 7;
      gload16(src + (size_t)(bn + h * 128 + f * 16 + l15) * K + T * 32 + l4 * 8,
              ldsb + ((g < 8) ? 98304 : 131072) + s * 16384 + h * 8192 + f * 1024);
    }
  };

  bf16x8 ah[4], al[4], bh[4], bl[4];
  auto readA = [&](int slot, int ih) {
#pragma unroll
    for (int i = 0; i < 4; ++i) {
      const int off = slot * 16384 + wm * 8192 + (ih * 4 + i) * 1024 + lane * 16;
      ah[i] = *(const bf16x8*)(ldsb + off);
      al[i] = *(const bf16x8*)(ldsb + 49152 + off);
    }
  };
  auto readBall = [&](int sB) {
#pragma unroll
    for (int j = 0; j < 4; ++j) {
      const int off = sB * 16384 + bhalf * 8192 + (jn * 4 + j) * 1024 + lane * 16;
      bh[j] = *(const bf16x8*)(ldsb + 98304 + off);
      bl[j] = *(const bf16x8*)(ldsb + 131072 + off);
    }
  };

#define QUAD48(IH)                                                             \
  _Pragma("unroll") for (int i = 0; i < 4; ++i) {                              \
    _Pragma("unroll") for (int j = 0; j < 4; ++j) {                            \
      f32x4 a = acc[(IH)*4 + i][j];                                            \
      a = __builtin_amdgcn_mfma_f32_16x16x32_bf16(bh[j], ah[i], a, 0, 0, 0);   \
      a = __builtin_amdgcn_mfma_f32_16x16x32_bf16(bl[j], ah[i], a, 0, 0, 0);   \
      a = __builtin_amdgcn_mfma_f32_16x16x32_bf16(bh[j], al[i], a, 0, 0, 0);   \
      acc[(IH)*4 + i][j] = a;                                                  \
    }                                                                          \
  }

  // prologue: B(0), A(0), B(1), A(1) -- 16 loads; vmcnt(8) lands B(0)+A(0)
  stageB(0, 0); stageB(0, 1);
  stageA(Ahi, 0, 0, 0); stageA(Alo, 0, 0, 49152);
  stageB(1, 0); stageB(1, 1);
  stageA(Ahi, 1, 1, 0); stageA(Alo, 1, 1, 49152);
  asm volatile("s_waitcnt vmcnt(8)" ::: "memory");
  __builtin_amdgcn_sched_barrier(0);
  __builtin_amdgcn_s_barrier();
  __builtin_amdgcn_sched_barrier(0);

  int aS = 0, aS2 = 2;  // t%3, (t+2)%3
  for (int t = 0; t < nt - 2; ++t) {
    const int sB = t & 1;
    // p0
    readA(aS, 0);
    readBall(sB);
    __builtin_amdgcn_sched_barrier(0);
    stageA(Ahi, t + 2, aS2, 0); stageA(Alo, t + 2, aS2, 49152);
    QUAD48(0);
    __builtin_amdgcn_sched_barrier(0);
    __builtin_amdgcn_s_barrier();  // B(t) reads retired -> B restage ok
    __builtin_amdgcn_sched_barrier(0);
    // p1
    readA(aS, 1);
    __builtin_amdgcn_sched_barrier(0);
    stageB(t + 2, 0); stageB(t + 2, 1);
    QUAD48(1);
    asm volatile("s_waitcnt vmcnt(8)" ::: "memory");
    __builtin_amdgcn_sched_barrier(0);
    __builtin_amdgcn_s_barrier();
    __builtin_amdgcn_sched_barrier(0);
    aS = (aS == 2) ? 0 : aS + 1;
    aS2 = (aS2 == 2) ? 0 : aS2 + 1;
  }
  // tail t = nt-2
  {
    const int sB = (nt - 2) & 1;
    readA(aS, 0);
    readBall(sB);
    QUAD48(0);
    readA(aS, 1);
    QUAD48(1);
    asm volatile("s_waitcnt vmcnt(0)" ::: "memory");
    __builtin_amdgcn_sched_barrier(0);
    __builtin_amdgcn_s_barrier();
    __builtin_amdgcn_sched_barrier(0);
    aS = (aS == 2) ? 0 : aS + 1;
  }
  // tail t = nt-1
  {
    const int sB = (nt - 1) & 1;
    readA(aS, 0);
    readBall(sB);
    QUAD48(0);
    readA(aS, 1);
    QUAD48(1);
  }
#undef QUAD48

  // epilogue: lane holds C[row=bm+wm*128+i*16+l15][col=bn+wn*64+j*16+l4*4+q]
#pragma unroll
  for (int i = 0; i < 8; ++i) {
    const int grow = bm + wm * 128 + i * 16 + l15;
#pragma unroll
    for (int j = 0; j < 4; ++j) {
      const int gcol = bn + wn * 64 + j * 16 + l4 * 4;
      const float4 bb = *(const float4*)&bias[gcol];
      float v0 = fmaxf(acc[i][j][0] + bb.x, 0.f);
      float v1 = fmaxf(acc[i][j][1] + bb.y, 0.f);
      float v2 = fmaxf(acc[i][j][2] + bb.z, 0.f);
      float v3 = fmaxf(acc[i][j][3] + bb.w, 0.f);
      short4 h, l;
      h.x = f2bf(v0); l.x = f2bf(v0 - bf2f(h.x));
      h.y = f2bf(v1); l.y = f2bf(v1 - bf2f(h.y));
      h.z = f2bf(v2); l.z = f2bf(v2 - bf2f(h.z));
      h.w = f2bf(v3); l.w = f2bf(v3 - bf2f(h.w));
      *(short4*)&Chi[(size_t)grow * N + gcol] = h;
      *(short4*)&Clo[(size_t)grow * N + gcol] = l;
    }
  }
}

// ============ L3 GEMM: 128x256 tile, 16x16x32 bf16x3, champion schedule ========
// Structural sibling of gemm_2bar with M-tile halved (full-chip grid at N=512).
// Wave tile 64x64 (acc 4x4). A = 3-slot ring (8KB/slot/op), B = 2-slot (16KB).
// LDS: Ahi 3x8K @0, Alo 3x8K @24576, Bhi 2x16K @49152, Blo 2x16K @81920 = 112KB.
// 6 gloads/wave/tile -> counted vmcnt(6). f32 out, no relu.
__global__ __launch_bounds__(512, 2) void gemm_l3(
    const u16* __restrict__ Ahi, const u16* __restrict__ Alo,
    const u16* __restrict__ Bhi, const u16* __restrict__ Blo,
    const float* __restrict__ bias, float* __restrict__ Cf,
    int M, int N, int K, size_t strideAe) {
  const int e = blockIdx.x;
  Ahi += (size_t)e * strideAe;
  Alo += (size_t)e * strideAe;
  Bhi += (size_t)e * (size_t)N * K;
  Blo += (size_t)e * (size_t)N * K;
  bias += (size_t)e * N;
  Cf += (size_t)e * (size_t)M * N;

  const int bm = blockIdx.y * 128, bn = blockIdx.z * 256;
  __shared__ __align__(16) char ldsb[114688];
  const int lane = threadIdx.x & 63, wid = threadIdx.x >> 6;
  const int wm = wid >> 2, wn = wid & 3;
  const int l15 = lane & 15, l4 = lane >> 4;
  const int bhalf = wn >> 1, jn = wn & 1;

  f32x4 acc[4][4];
#pragma unroll
  for (int i = 0; i < 4; ++i)
#pragma unroll
    for (int j = 0; j < 4; ++j) acc[i][j] = (f32x4){0.f, 0.f, 0.f, 0.f};

  const int nt = K / 32;

  // stage both A ops (Ahi+Alo, 8 frags each) in one call: 2 gloads/wave
  auto stageA3 = [&](int T, int slot) {
#pragma unroll
    for (int q = 0; q < 2; ++q) {
      const int g = wid * 2 + q;  // <8: Ahi frag g, >=8: Alo frag g-8
      const u16* src = (g < 8) ? Ahi : Alo;
      const int f = g & 7;
      gload16(src + (size_t)(bm + f * 16 + l15) * K + T * 32 + l4 * 8,
              ldsb + ((g < 8) ? 0 : 24576) + slot * 8192 + f * 1024);
    }
  };
  auto stageB = [&](int T, int h) {
    const int s = T & 1;
#pragma unroll
    for (int q = 0; q < 2; ++q) {
      const int g = wid * 2 + q;  // <8: Bhi frag g, >=8: Blo frag g-8
      const u16* src = (g < 8) ? Bhi : Blo;
      const int f = g & 7;
      gload16(src + (size_t)(bn + h * 128 + f * 16 + l15) * K + T * 32 + l4 * 8,
              ldsb + ((g < 8) ? 49152 : 81920) + s * 16384 + h * 8192 + f * 1024);
    }
  };

  bf16x8 ah[2], al[2], bh[4], bl[4];
  auto readA = [&](int slot, int ih) {
#pragma unroll
    for (int i = 0; i < 2; ++i) {
      const int off = slot * 8192 + (wm * 4 + ih * 2 + i) * 1024 + lane * 16;
      ah[i] = *(const bf16x8*)(ldsb + off);
      al[i] = *(const bf16x8*)(ldsb + 24576 + off);
    }
  };
  auto readBall = [&](int sB) {
#pragma unroll
    for (int j = 0; j < 4; ++j) {
      const int off = sB * 16384 + bhalf * 8192 + (jn * 4 + j) * 1024 + lane * 16;
      bh[j] = *(const bf16x8*)(ldsb + 49152 + off);
      bl[j] = *(const bf16x8*)(ldsb + 81920 + off);
    }
  };

#define QUAD24(IH)                                                             \
  _Pragma("unroll") for (int i = 0; i < 2; ++i) {                              \
    _Pragma("unroll") for (int j = 0; j < 4; ++j) {                            \
      f32x4 a = acc[(IH)*2 + i][j];                                            \
      a = __builtin_amdgcn_mfma_f32_16x16x32_bf16(bh[j], ah[i], a, 0, 0, 0);   \
      a = __builtin_amdgcn_mfma_f32_16x16x32_bf16(bl[j], ah[i], a, 0, 0, 0);   \
      a = __builtin_amdgcn_mfma_f32_16x16x32_bf16(bh[j], al[i], a, 0, 0, 0);   \
      acc[(IH)*2 + i][j] = a;                                                  \
    }                                                                          \
  }

  // prologue: B(0)[4], A(0)[2], B(1)[4], A(1)[2]; vmcnt(6) lands B(0)+A(0)
  stageB(0, 0); stageB(0, 1);
  stageA3(0, 0);
  stageB(1, 0); stageB(1, 1);
  stageA3(1, 1);
  asm volatile("s_waitcnt vmcnt(6)" ::: "memory");
  __builtin_amdgcn_sched_barrier(0);
  __builtin_amdgcn_s_barrier();
  __builtin_amdgcn_sched_barrier(0);

  int aS = 0, aS2 = 2;  // t%3, (t+2)%3
  for (int t = 0; t < nt - 2; ++t) {
    const int sB = t & 1;
    // p0: reads + stage A(t+2); B regs consumed by QUAD24(0) before barrier
    readA(aS, 0);
    readBall(sB);
    __builtin_amdgcn_sched_barrier(0);
    stageA3(t + 2, aS2);
    QUAD24(0);
    __builtin_amdgcn_sched_barrier(0);
    __builtin_amdgcn_s_barrier();  // B(t) reads retired -> B restage ok
    __builtin_amdgcn_sched_barrier(0);
    // p1
    readA(aS, 1);
    __builtin_amdgcn_sched_barrier(0);
    stageB(t + 2, 0); stageB(t + 2, 1);
    QUAD24(1);
    // leave A(t+2)[2]+B(t+2)[4] in flight; forces A(t+1),B(t+1) landed
    asm volatile("s_waitcnt vmcnt(6)" ::: "memory");
    __builtin_amdgcn_sched_barrier(0);
    __builtin_amdgcn_s_barrier();
    __builtin_amdgcn_sched_barrier(0);
    aS = (aS == 2) ? 0 : aS + 1;
    aS2 = (aS2 == 2) ? 0 : aS2 + 1;
  }
  // tail t = nt-2: no staging; drain for last tile
  {
    const int sB = (nt - 2) & 1;
    readA(aS, 0);
    readBall(sB);
    QUAD24(0);
    readA(aS, 1);
    QUAD24(1);
    asm volatile("s_waitcnt vmcnt(0)" ::: "memory");
    __builtin_amdgcn_sched_barrier(0);
    __builtin_amdgcn_s_barrier();
    __builtin_amdgcn_sched_barrier(0);
    aS = (aS == 2) ? 0 : aS + 1;
  }
  // tail t = nt-1
  {
    const int sB = (nt - 1) & 1;
    readA(aS, 0);
    readBall(sB);
    QUAD24(0);
    readA(aS, 1);
    QUAD24(1);
  }
#undef QUAD24

  // epilogue: lane holds C[row=bm+wm*64+i*16+l15][col=bn+wn*64+j*16+l4*4+q]
#pragma unroll
  for (int i = 0; i < 4; ++i) {
    const int grow = bm + wm * 64 + i * 16 + l15;
#pragma unroll
    for (int j = 0; j < 4; ++j) {
      const int gcol = bn + wn * 64 + j * 16 + l4 * 4;
      const float4 bb = *(const float4*)&bias[gcol];
      *(float4*)&Cf[(size_t)grow * N + gcol] =
          make_float4(acc[i][j][0] + bb.x, acc[i][j][1] + bb.y,
                      acc[i][j][2] + bb.z, acc[i][j][3] + bb.w);
    }
  }
}

// ---------------- gate layer 1 (+ fused x -> hi/lo pack) ----------------
__global__ __launch_bounds__(256) void gate1_kernel(
    const float* __restrict__ x, const float* __restrict__ Wg1,
    const float* __restrict__ bg1, float* __restrict__ g,
    u16* __restrict__ xhi, u16* __restrict__ xlo) {
  __shared__ float xs[8 * 1024];
  const int b0 = blockIdx.x * 8;
  const size_t base = (size_t)b0 * INF;
  const float* xp = x + base;
  for (int idx = threadIdx.x * 4; idx < 8 * 1024; idx += 1024) {
    float4 v = *(const float4*)&xp[idx];
    *(float4*)&xs[idx] = v;
    short4 h, l;
    h.x = f2bf(v.x); l.x = f2bf(v.x - bf2f(h.x));
    h.y = f2bf(v.y); l.y = f2bf(v.y - bf2f(h.y));
    h.z = f2bf(v.z); l.z = f2bf(v.z - bf2f(h.z));
    h.w = f2bf(v.w); l.w = f2bf(v.w - bf2f(h.w));
    *(short4*)&xhi[base + idx] = h;
    *(short4*)&xlo[base + idx] = l;
  }
  __syncthreads();
  const int t = threadIdx.x;
  float acc[8] = {0, 0, 0, 0, 0, 0, 0, 0};
  for (int i = 0; i < INF; ++i) {
    float w = Wg1[(size_t)i * G + t];
#pragma unroll
    for (int r = 0; r < 8; ++r) acc[r] = fmaf(xs[r * 1024 + i], w, acc[r]);
  }
  const float bb = bg1[t];
#pragma unroll
  for (int r = 0; r < 8; ++r)
    g[(size_t)(b0 + r) * G + t] = fmaxf(acc[r] + bb, 0.0f);
}

// ---------------- gate layer 2 + softmax ----------------
__global__ __launch_bounds__(64) void gate2_kernel(
    const float* __restrict__ g, const float* __restrict__ Wg2,
    const float* __restrict__ bg2, float* __restrict__ gw) {
  const int b = blockIdx.x, lane = threadIdx.x;
  float4 gv = *(const float4*)(g + (size_t)b * G + lane * 4);
  float p[8];
#pragma unroll
  for (int e = 0; e < 8; ++e) {
    int j = lane * 4;
    float s = gv.x * Wg2[(j + 0) * 8 + e] + gv.y * Wg2[(j + 1) * 8 + e] +
              gv.z * Wg2[(j + 2) * 8 + e] + gv.w * Wg2[(j + 3) * 8 + e];
    p[e] = waveAllSum(s);
  }
  if (lane == 0) {
    float l[8];
    float mx = -1e30f;
#pragma unroll
    for (int e = 0; e < 8; ++e) {
      l[e] = p[e] + bg2[e];
      mx = fmaxf(mx, l[e]);
    }
    float sum = 0.0f;
#pragma unroll
    for (int e = 0; e < 8; ++e) {
      l[e] = expf(l[e] - mx);
      sum += l[e];
    }
    float inv = 1.0f / sum;
#pragma unroll
    for (int e = 0; e < 8; ++e) gw[(size_t)b * 8 + e] = l[e] * inv;
  }
}

// ---------------- Gram-Schmidt + combine + out-proj ----------------
__global__ __launch_bounds__(256) void gs_kernel(
    const float* __restrict__ eo, const float* __restrict__ gw,
    const float* __restrict__ Wo, const float* __restrict__ bo,
    float* __restrict__ out, int CB) {
  const int lane = threadIdx.x & 63;
  const int b = blockIdx.x * 4 + (threadIdx.x >> 6);
  const size_t ES = (size_t)CB * OUTD;
  const float* base = eo + (size_t)b * OUTD + lane * 8;
  float vs[8][8];
  float denom[8];
#pragma unroll
  for (int i = 0; i < 8; ++i) {
    float cur[8];
    float4 u0 = *(const float4*)(base + (size_t)i * ES);
    float4 u1 = *(const float4*)(base + (size_t)i * ES + 4);
    cur[0] = u0.x; cur[1] = u0.y; cur[2] = u0.z; cur[3] = u0.w;
    cur[4] = u1.x; cur[5] = u1.y; cur[6] = u1.z; cur[7] = u1.w;
#pragma unroll
    for (int j = 0; j < i; ++j) {
      float dp = 0.0f;
#pragma unroll
      for (int d = 0; d < 8; ++d) dp = fmaf(cur[d], vs[j][d], dp);
      dp = waveAllSum(dp);
      float coeff = dp / (denom[j] + 1e-6f);
#pragma unroll
      for (int d = 0; d < 8; ++d) cur[d] = fmaf(-coeff, vs[j][d], cur[d]);
    }
    float nn = 0.0f;
#pragma unroll
    for (int d = 0; d < 8; ++d) nn = fmaf(cur[d], cur[d], nn);
    nn = waveAllSum(nn);
    float inv = 1.0f / fmaxf(sqrtf(nn), 1e-6f);
#pragma unroll
    for (int d = 0; d < 8; ++d) vs[i][d] = cur[d] * inv;
    float dd = 0.0f;
#pragma unroll
    for (int d = 0; d < 8; ++d) dd = fmaf(vs[i][d], vs[i][d], dd);
    denom[i] = waveAllSum(dd);
  }
  float gwv[8];
#pragma unroll
  for (int e = 0; e < 8; ++e) gwv[e] = gw[(size_t)b * 8 + e];
  float part = 0.0f;
#pragma unroll
  for (int d = 0; d < 8; ++d) {
    float c = 0.0f;
#pragma unroll
    for (int e = 0; e < 8; ++e) c = fmaf(vs[e][d], gwv[e], c);
    part = fmaf(c, Wo[lane * 8 + d], part);
  }
  part = waveAllSum(part);
  if (lane == 0) out[b] = part + bo[0];
}

extern "C" void kernel_launch(void* const* d_in, const int* in_sizes, int n_in,
                              void* d_out, int out_size, void* d_ws, size_t ws_size,
                              hipStream_t stream) {
  const float* x   = (const float*)d_in[0];
  const float* W1  = (const float*)d_in[1];
  const float* b1  = (const float*)d_in[2];
  const float* W2  = (const float*)d_in[3];
  const float* b2  = (const float*)d_in[4];
  const float* W3  = (const float*)d_in[5];
  const float* b3  = (const float*)d_in[6];
  const float* Wg1 = (const float*)d_in[7];
  const float* bg1 = (const float*)d_in[8];
  const float* Wg2 = (const float*)d_in[9];
  const float* bg2 = (const float*)d_in[10];
  const float* Wo  = (const float*)d_in[11];
  const float* bo  = (const float*)d_in[12];
  float* out = (float*)d_out;

  char* p = (char*)d_ws;
  float* gw = (float*)p;          p += (size_t)(128u << 10);
  float* g  = (float*)p;          p += (size_t)(4u << 20);
  u16* xhi = (u16*)p;             p += (size_t)Bsz * INF * 2;
  u16* xlo = (u16*)p;             p += (size_t)Bsz * INF * 2;
  u16* w1h = (u16*)p;             p += (size_t)NE * H1 * INF * 2;
  u16* w1l = (u16*)p;             p += (size_t)NE * H1 * INF * 2;
  u16* w2h = (u16*)p;             p += (size_t)NE * H2 * H1 * 2;
  u16* w2l = (u16*)p;             p += (size_t)NE * H2 * H1 * 2;
  u16* w3h = (u16*)p;             p += (size_t)NE * OUTD * H2 * 2;
  u16* w3l = (u16*)p;             p += (size_t)NE * OUTD * H2 * 2;
  const size_t fixedBytes = (size_t)(p - (char*)d_ws);

  // chunk region: h1 hi/lo + h2 hi/lo = CB*128KB; CB multiple of 256
  int CB = 4096;
  while (CB > 256 && fixedBytes + (size_t)CB * (size_t)(128u << 10) > ws_size) CB >>= 1;
  u16* h1h = (u16*)p;
  u16* h1l = h1h + (size_t)NE * CB * H1;
  u16* h2h = h1l + (size_t)NE * CB * H1;
  u16* h2l = h2h + (size_t)NE * CB * H2;
  float* eo = (float*)h1h;  // layer-3 f32 out reuses h1 region (dead by then)

  hipMemsetAsync(d_out, 0, (size_t)out_size * sizeof(float), stream);

  // gate1 also packs x -> xhi/xlo (x rows pass through its registers anyway)
  gate1_kernel<<<Bsz / 8, 256, 0, stream>>>(x, Wg1, bg1, g, xhi, xlo);
  gate2_kernel<<<Bsz, 64, 0, stream>>>(g, Wg2, bg2, gw);

  pack_wt<<<dim3(H1 / 32, INF / 32, NE), 256, 0, stream>>>(W1, w1h, w1l, INF, H1);
  pack_wt<<<dim3(H2 / 32, H1 / 32, NE), 256, 0, stream>>>(W2, w2h, w2l, H1, H2);
  pack_wt<<<dim3(OUTD / 32, H2 / 32, NE), 256, 0, stream>>>(W3, w3h, w3l, H2, OUTD);

  for (int c0 = 0; c0 < Bsz; c0 += CB) {
    gemm_2bar<<<dim3(NE, CB / 256, H1 / 256), 512, 0, stream>>>(
        xhi + (size_t)c0 * INF, xlo + (size_t)c0 * INF, w1h, w1l, b1,
        h1h, h1l, CB, H1, INF, (size_t)0);
    gemm_2bar<<<dim3(NE, CB / 256, H2 / 256), 512, 0, stream>>>(
        h1h, h1l, w2h, w2l, b2, h2h, h2l, CB, H2, H1, (size_t)CB * H1);
    gemm_l3<<<dim3(NE, CB / 128, OUTD / 256), 512, 0, stream>>>(
        h2h, h2l, w3h, w3l, b3, eo, CB, OUTD, H2, (size_t)CB * H2);
    gs_kernel<<<CB / 4, 256, 0, stream>>>(eo, gw + (size_t)c0 * NE, Wo, bo,
                                          out + c0, CB);
  }
}